// Round 8
// baseline (1135.261 us; speedup 1.0000x reference)
//
#include <hip/hip_runtime.h>
#include <hip/hip_bf16.h>
#include <math.h>

// ---------------- problem constants ----------------
#define D        256
#define NINNER   2048
#define NROW     2049          // 2048 + dustbin
#define SP       2064          // padded row stride (floats), 16B-aligned rows
#define ITERS_N  100
#define EPS_F    0.8f
#define TAU_F    1.02f
#define NB       256           // persistent blocks
#define NT       256           // threads per block

typedef unsigned long long u64;

// value exchange: u64 atoms = 2 packed floats, freshness = SIGN BITS
// (tag k -> sign (k>>1)&1; parity k&1 picks the buffer). 1024 pairs = 2048 floats.
#define PSTRIDE  1088u         // u64s per buffer (1024 used + dustbin float slot 2048 + pad)
#define SGNMASK  0x8000000080000000ull

// ws layout (in floats)
#define SZ_MAT   (2049u * 2064u)          // 4229136
#define OFF_E    0u
#define OFF_F    SZ_MAT
#define OFF_WUP  (2u * SZ_MAT)                  // u64[2][PSTRIDE] = 2*2*PSTRIDE floats
#define OFF_WVP  (OFF_WUP + 4u * PSTRIDE)
#define OFF_MAX0 (OFF_WVP + 4u * PSTRIDE)
#define OFF_IDX0 (OFF_MAX0 + 2048u)
#define OFF_IDX1 (OFF_IDX0 + 2048u)
#define OFF_MS0  (OFF_IDX1 + 2048u)
#define OFF_VLD0 (OFF_MS0 + 2048u)

// d_out layout (floats)
#define OOFF_Z   0u
#define OOFF_I0  (2049u * 2049u)          // 4198401
#define OOFF_I1  (OOFF_I0 + 2048u)
#define OOFF_S0  (OOFF_I1 + 2048u)
#define OOFF_S1  (OOFF_S0 + 2048u)

__device__ __forceinline__ u64 pack_pair(float lo, float hi, unsigned sbit31) {
    return ((u64)(__float_as_uint(hi) | sbit31) << 32)
         |  (u64)(__float_as_uint(lo) | sbit31);
}

// ---------------- K1: fp32 GEMM -> E = exp(scores), F = E^T (fused) ----------------
__global__ __launch_bounds__(256) void k_gemm(const float* __restrict__ A,
                                              const float* __restrict__ Bm,
                                              float* __restrict__ E,
                                              float* __restrict__ F) {
    __shared__ float As[8][64];
    __shared__ float Bs[8][64];
    const int tid = threadIdx.x;
    const int tx = tid & 15, ty = tid >> 4;
    const int row0 = blockIdx.y * 64, col0 = blockIdx.x * 64;
    float acc[4][4] = {};
    const int lr = tid >> 6, lc = tid & 63;
    for (int k0 = 0; k0 < D; k0 += 8) {
        As[lr][lc]     = A[(k0 + lr) * NINNER + row0 + lc];
        As[lr + 4][lc] = A[(k0 + lr + 4) * NINNER + row0 + lc];
        Bs[lr][lc]     = Bm[(k0 + lr) * NINNER + col0 + lc];
        Bs[lr + 4][lc] = Bm[(k0 + lr + 4) * NINNER + col0 + lc];
        __syncthreads();
#pragma unroll
        for (int kk = 0; kk < 8; ++kk) {
            const float4 av = *(const float4*)&As[kk][ty * 4];
            const float4 bv = *(const float4*)&Bs[kk][tx * 4];
            const float a_[4] = {av.x, av.y, av.z, av.w};
            const float b_[4] = {bv.x, bv.y, bv.z, bv.w};
#pragma unroll
            for (int r = 0; r < 4; ++r)
#pragma unroll
                for (int c = 0; c < 4; ++c)
                    acc[r][c] = fmaf(a_[r], b_[c], acc[r][c]);
        }
        __syncthreads();
    }
    float o[4][4];
#pragma unroll
    for (int r = 0; r < 4; ++r)
#pragma unroll
        for (int c = 0; c < 4; ++c)
            o[r][c] = expf(acc[r][c] * 0.0625f);
    const int row = row0 + ty * 4, col = col0 + tx * 4;
#pragma unroll
    for (int r = 0; r < 4; ++r)     // E tile
        *(float4*)(E + (size_t)(row + r) * SP + col)
            = make_float4(o[r][0], o[r][1], o[r][2], o[r][3]);
#pragma unroll
    for (int c = 0; c < 4; ++c)     // F tile (transposed)
        *(float4*)(F + (size_t)(col + c) * SP + row)
            = make_float4(o[0][c], o[1][c], o[2][c], o[3][c]);
}

// ---------------- K2: bins + exchange-buffer init ----------------
// wv parity0 = real tag-0 values (+1.0, sign 0). The other three buffer halves
// get the OPPOSITE sign of their first-wanted tag, so stale/poison never passes:
//   wu parity0 first want tag2 (s=1) -> init +1 (s=0)
//   wu parity1 first want tag1 (s=0) -> init -1 (s=1)
//   wv parity1 first want tag1 (s=0) -> init -1 (s=1)
__global__ __launch_bounds__(256) void k_init(float* __restrict__ E,
                                              float* __restrict__ F,
                                              u64* __restrict__ wub,
                                              u64* __restrict__ wvb,
                                              const float* __restrict__ alpha) {
    const int t = blockIdx.x * 256 + threadIdx.x;
    const float ea = expf(alpha[0]);
    if (t < NINNER) {
        E[(size_t)t * SP + NINNER] = ea;        // E bin column (epilogue only)
        F[(size_t)t * SP + NINNER] = ea;        // F bin column
    }
    if (t <= NINNER) {
        E[(size_t)NINNER * SP + t] = ea;        // E bin row (+corner)
        F[(size_t)NINNER * SP + t] = ea;        // F bin row (+corner)
    }
    if (t < 1024) {
        const u64 pos = pack_pair(1.0f, 1.0f, 0u);
        const u64 neg = pack_pair(1.0f, 1.0f, 0x80000000u);
        wvb[t]           = pos;                 // real wv(0) = 1.0, tag 0
        wvb[PSTRIDE + t] = neg;
        wub[t]           = pos;                 // placeholder, mismatches s=1
        wub[PSTRIDE + t] = neg;                 // placeholder, mismatches s=0
    }
}

// ---------------- poll 4 pair-atoms from ONE producer (sign-bit freshness) -------
__device__ __forceinline__ void poll4(const u64* __restrict__ buf, int tid,
                                      u64 expect, float* w) {
    u64 a[4];
#pragma unroll
    for (int k = 0; k < 4; ++k)
        a[k] = __hip_atomic_load(buf + 4 * tid + k, __ATOMIC_RELAXED, __HIP_MEMORY_SCOPE_AGENT);
    for (;;) {
        unsigned miss = 0u;
#pragma unroll
        for (int k = 0; k < 4; ++k)
            miss |= (((a[k] ^ expect) & SGNMASK) != 0ull) ? (1u << k) : 0u;
        if (!miss) break;
        __builtin_amdgcn_s_sleep(1);
#pragma unroll
        for (int k = 0; k < 4; ++k)
            if (miss & (1u << k))
                a[k] = __hip_atomic_load(buf + 4 * tid + k, __ATOMIC_RELAXED, __HIP_MEMORY_SCOPE_AGENT);
    }
#pragma unroll
    for (int k = 0; k < 4; ++k) {
        w[2 * k]     = fabsf(__uint_as_float((unsigned)a[k]));
        w[2 * k + 1] = fabsf(__uint_as_float((unsigned)(a[k] >> 32)));
    }
}

// ---------------- K3: persistent Sinkhorn — sign-tagged pair dataflow ----------------
// Thread tid consumes cols [8*tid, 8*tid+8) => its values come from EXACTLY one
// producer (block tid): single-producer gating, 4 u64 polls/thread, one store
// visibility hop, no flags, no fences, no post-publish barrier. Dustbin
// potentials locally replicated (see r6). Overwrite safety: causal chain
// guarantees consumer read of tag k precedes producer write of tag k+2.
__global__ __launch_bounds__(256, 1) void k_sinkhorn(const float* __restrict__ E,
                                                     const float* __restrict__ F,
                                                     u64* wub, u64* wvb,
                                                     const float* __restrict__ alpha) {
    const int b = blockIdx.x, tid = threadIdx.x;
    const int lane = tid & 63, wid = tid >> 6;
    const int base = b * 8;
    const bool lastb = (b == NB - 1);
    __shared__ float red[2][4][9];

    const float norm = -8.317766166719343f;            // -log(4096)
    const float logbin = 7.624618986159398f + norm;     // log(2048) + norm
    const float ea = expf(alpha[0]);

    // register-resident fragments: eR[r][q] = E[base+r][8*tid+q]
    float eR[8][8], fR[8][8];
#pragma unroll
    for (int r = 0; r < 8; ++r) {
        const float* rowE = E + (size_t)(base + r) * SP + 8 * tid;
        const float* rowF = F + (size_t)(base + r) * SP + 8 * tid;
        const float4 e0 = *(const float4*)rowE, e1 = *(const float4*)(rowE + 4);
        const float4 f0 = *(const float4*)rowF, f1 = *(const float4*)(rowF + 4);
        eR[r][0] = e0.x; eR[r][1] = e0.y; eR[r][2] = e0.z; eR[r][3] = e0.w;
        eR[r][4] = e1.x; eR[r][5] = e1.y; eR[r][6] = e1.z; eR[r][7] = e1.w;
        fR[r][0] = f0.x; fR[r][1] = f0.y; fR[r][2] = f0.z; fR[r][3] = f0.w;
        fR[r][4] = f1.x; fR[r][5] = f1.y; fR[r][6] = f1.z; fR[r][7] = f1.w;
    }

    float u = 0.0f, v = 0.0f;              // potentials for row/col base+tid (tid<8)
    float ub = 0.0f, vb = 0.0f;            // dustbin potentials — local replicas
    float eub = 1.0f, evb = 1.0f;

    for (int it = 0; it < ITERS_N; ++it) {
        // ---- phase A: consume wv tag it, produce wu tag it+1 ----
        {
            const u64* src = wvb + (size_t)(it & 1) * PSTRIDE;
            u64* dst = wub + (size_t)((it + 1) & 1) * PSTRIDE;
            const u64 expw = ((it >> 1) & 1) ? SGNMASK : 0ull;
            const unsigned sbit = (((it + 1) >> 1) & 1) << 31;
            float w[8];
            poll4(src, tid, expw, w);
            float p[8];
#pragma unroll
            for (int r = 0; r < 8; ++r) {
                float s = 0.0f;
#pragma unroll
                for (int q = 0; q < 8; ++q) s = fmaf(eR[r][q], w[q], s);
                p[r] = s;
            }
            float t = w[0] + w[1] + w[2] + w[3] + w[4] + w[5] + w[6] + w[7];
#pragma unroll
            for (int r = 0; r < 8; ++r) {
                float s = p[r];
#pragma unroll
                for (int m = 1; m < 64; m <<= 1) s += __shfl_xor(s, m, 64);
                if (lane == 0) red[0][wid][r] = s;
            }
#pragma unroll
            for (int m = 1; m < 64; m <<= 1) t += __shfl_xor(t, m, 64);
            if (lane == 0) red[0][wid][8] = t;
            __syncthreads();
            float eu = 0.0f;
            if (tid < 8) {
                const float S = red[0][0][tid] + red[0][1][tid] + red[0][2][tid] + red[0][3][tid]
                              + ea * evb;
                const float unew = (norm - logf(S)) / TAU_F;
                u = u + EPS_F * (unew - u);
                eu = expf(u);
            }
            if (tid < 64) {                        // wave 0: pack + publish ASAP
                const float lo = __shfl(eu, 2 * tid, 64);
                const float hi = __shfl(eu, 2 * tid + 1, 64);
                if (tid < 4)
                    __hip_atomic_store(dst + 4 * b + tid, pack_pair(lo, hi, sbit),
                                       __ATOMIC_RELAXED, __HIP_MEMORY_SCOPE_AGENT);
            }
            // local dustbin update (all threads, identical result)
            const float tsum = red[0][0][8] + red[0][1][8] + red[0][2][8] + red[0][3][8];
            const float Sbin = ea * (tsum + evb);
            ub = ub + EPS_F * ((logbin - logf(Sbin)) / TAU_F - ub);
            eub = expf(ub);
        }
        // ---- phase B: consume wu tag it+1, produce wv tag it+1 ----
        {
            const u64* src = wub + (size_t)((it + 1) & 1) * PSTRIDE;
            u64* dst = wvb + (size_t)((it + 1) & 1) * PSTRIDE;
            const u64 expw = (((it + 1) >> 1) & 1) ? SGNMASK : 0ull;
            const unsigned sbit = (((it + 1) >> 1) & 1) << 31;
            float w[8];
            poll4(src, tid, expw, w);
            float p[8];
#pragma unroll
            for (int r = 0; r < 8; ++r) {
                float s = 0.0f;
#pragma unroll
                for (int q = 0; q < 8; ++q) s = fmaf(fR[r][q], w[q], s);
                p[r] = s;
            }
            float t = w[0] + w[1] + w[2] + w[3] + w[4] + w[5] + w[6] + w[7];
#pragma unroll
            for (int r = 0; r < 8; ++r) {
                float s = p[r];
#pragma unroll
                for (int m = 1; m < 64; m <<= 1) s += __shfl_xor(s, m, 64);
                if (lane == 0) red[1][wid][r] = s;
            }
#pragma unroll
            for (int m = 1; m < 64; m <<= 1) t += __shfl_xor(t, m, 64);
            if (lane == 0) red[1][wid][8] = t;
            __syncthreads();
            float ev = 0.0f;
            if (tid < 8) {
                const float T = red[1][0][tid] + red[1][1][tid] + red[1][2][tid] + red[1][3][tid]
                              + ea * eub;
                const float vnew = (norm - logf(T)) / TAU_F;
                v = v + EPS_F * (vnew - v);
                ev = expf(v);
            }
            if (tid < 64) {
                const float lo = __shfl(ev, 2 * tid, 64);
                const float hi = __shfl(ev, 2 * tid + 1, 64);
                if (tid < 4)
                    __hip_atomic_store(dst + 4 * b + tid, pack_pair(lo, hi, sbit),
                                       __ATOMIC_RELAXED, __HIP_MEMORY_SCOPE_AGENT);
            }
            const float tsum = red[1][0][8] + red[1][1][8] + red[1][2][8] + red[1][3][8];
            const float Tbin = ea * (tsum + eub);
            vb = vb + EPS_F * ((logbin - logf(Tbin)) / TAU_F - vb);
            evb = expf(vb);
        }
    }
    // final tag = 100 -> parity 0, sign 0 -> parity-0 buffers ARE plain float arrays.
    // Publish dustbin scalings into float slot 2048 for the epilogue.
    if (lastb && tid == 0) {
        ((float*)wub)[2048] = eub;
        ((float*)wvb)[2048] = evb;
    }
}

// ---------------- K4: fused epilogue — out0 = exp(Z), row argmax, col argmax ----------
__global__ __launch_bounds__(256) void k_finish(const float* __restrict__ E,
                                                const float* __restrict__ F,
                                                const float* __restrict__ wuf,
                                                const float* __restrict__ wvf,
                                                float* __restrict__ out,
                                                float* __restrict__ max0,
                                                int* __restrict__ idx0,
                                                int* __restrict__ idx1) {
    const int i = blockIdx.x;                 // 0..2048
    const int tid = threadIdx.x;
    const int lane = tid & 63, wid = tid >> 6;
    __shared__ float sb[4]; __shared__ int si[4];

    // --- row part: write out row i, argmax over inner cols ---
    {
        const float wui = wuf[i] * 4096.0f;       // * exp(-norm)
        const float* row = E + (size_t)i * SP;
        float best = -1.0f; int bidx = 0;
        for (int j = tid; j < NROW; j += 256) {
            const float val = row[j] * wvf[j] * wui;
            out[(size_t)i * NROW + j] = val;
            if (j < NINNER && val > best) { best = val; bidx = j; }
        }
        if (i < NINNER) {
#pragma unroll
            for (int m = 1; m < 64; m <<= 1) {
                const float ob = __shfl_xor(best, m, 64);
                const int   oi = __shfl_xor(bidx, m, 64);
                if (ob > best || (ob == best && oi < bidx)) { best = ob; bidx = oi; }
            }
            if (lane == 0) { sb[wid] = best; si[wid] = bidx; }
            __syncthreads();
            if (tid == 0) {
                for (int k = 1; k < 4; ++k)
                    if (sb[k] > best || (sb[k] == best && si[k] < bidx)) { best = sb[k]; bidx = si[k]; }
                max0[i] = best; idx0[i] = bidx;
            }
        }
    }

    // --- col part: argmax of column i over inner rows (via F) ---
    if (i < NINNER) {
        __syncthreads();                          // sb/si reuse safety
        const float* row = F + (size_t)i * SP;
        float best = -1.0f; int bidx = 0;
        for (int r = tid; r < NINNER; r += 256) {
            const float q = row[r] * wuf[r];
            if (q > best) { best = q; bidx = r; }
        }
#pragma unroll
        for (int m = 1; m < 64; m <<= 1) {
            const float ob = __shfl_xor(best, m, 64);
            const int   oi = __shfl_xor(bidx, m, 64);
            if (ob > best || (ob == best && oi < bidx)) { best = ob; bidx = oi; }
        }
        if (lane == 0) { sb[wid] = best; si[wid] = bidx; }
        __syncthreads();
        if (tid == 0) {
            for (int k = 1; k < 4; ++k)
                if (sb[k] > best || (sb[k] == best && si[k] < bidx)) { best = sb[k]; bidx = si[k]; }
            idx1[i] = bidx;
        }
    }
}

// ---------------- K5a/K5b: mutual matching ----------------
__global__ __launch_bounds__(256) void k_match0(const float* __restrict__ max0,
                                                const int* __restrict__ idx0,
                                                const int* __restrict__ idx1,
                                                float* __restrict__ ms0,
                                                int* __restrict__ vld0,
                                                float* __restrict__ out) {
    const int i = blockIdx.x * 256 + threadIdx.x;
    if (i >= NINNER) return;
    const int j = idx0[i];
    const bool mut = (idx1[j] == i);
    const float ms = mut ? max0[i] : 0.0f;
    const bool val = mut && (ms > 0.2f);
    ms0[i] = ms; vld0[i] = val ? 1 : 0;
    out[OOFF_I0 + i] = val ? (float)j : -1.0f;
    out[OOFF_S0 + i] = ms;
}
__global__ __launch_bounds__(256) void k_match1(const int* __restrict__ idx0,
                                                const int* __restrict__ idx1,
                                                const float* __restrict__ ms0,
                                                const int* __restrict__ vld0,
                                                float* __restrict__ out) {
    const int j = blockIdx.x * 256 + threadIdx.x;
    if (j >= NINNER) return;
    const int i = idx1[j];
    const bool mut = (idx0[i] == j);
    const float ms = mut ? ms0[i] : 0.0f;
    const bool val = mut && (vld0[i] != 0);
    out[OOFF_I1 + j] = val ? (float)i : -1.0f;
    out[OOFF_S1 + j] = ms;
}

// ---------------- host ----------------
extern "C" void kernel_launch(void* const* d_in, const int* in_sizes, int n_in,
                              void* d_out, int out_size, void* d_ws, size_t ws_size,
                              hipStream_t stream) {
    const float* A     = (const float*)d_in[0];   // mdesc0 (1,256,2048)
    const float* Bm    = (const float*)d_in[1];   // mdesc1 (1,256,2048)
    const float* alpha = (const float*)d_in[2];   // bin_score scalar

    float* ws = (float*)d_ws;
    float* E    = ws + OFF_E;
    float* F    = ws + OFF_F;
    u64*   wub  = (u64*)(ws + OFF_WUP);
    u64*   wvb  = (u64*)(ws + OFF_WVP);
    float* max0 = ws + OFF_MAX0;
    int*   idx0 = (int*)(ws + OFF_IDX0);
    int*   idx1 = (int*)(ws + OFF_IDX1);
    float* ms0  = ws + OFF_MS0;
    int*   vld0 = (int*)(ws + OFF_VLD0);
    float* out  = (float*)d_out;

    k_gemm<<<dim3(32, 32), 256, 0, stream>>>(A, Bm, E, F);
    k_init<<<dim3(9), 256, 0, stream>>>(E, F, wub, wvb, alpha);
    k_sinkhorn<<<dim3(NB), NT, 0, stream>>>(E, F, wub, wvb, alpha);
    // final tag 100 (parity 0, sign 0) -> parity-0 buffers are plain float arrays
    k_finish<<<dim3(NROW), 256, 0, stream>>>(E, F, (const float*)wub, (const float*)wvb,
                                             out, max0, idx0, idx1);
    k_match0<<<dim3(8), 256, 0, stream>>>(max0, idx0, idx1, ms0, vld0, out);
    k_match1<<<dim3(8), 256, 0, stream>>>(idx0, idx1, ms0, vld0, out);
}